// Round 1
// baseline (768.573 us; speedup 1.0000x reference)
//
#include <hip/hip_runtime.h>
#include <hip/hip_bf16.h>

constexpr int N_NODES = 100000;
constexpr int N_EDGES = 3200000;
constexpr int D = 128;

constexpr int SCAN_LEN = N_NODES + 1;          // 100001
constexpr int SCAN_BLOCKS = (SCAN_LEN + 255) / 256;  // 391

// ---------------------------------------------------------------------------
// K1: h = x @ W^T + b.   64-row x 64-col tiles, 256 threads, acc[4][4]/thread.
// Wt (transposed W half) + x tile staged in LDS; 2 blocks/CU (66.5 KB LDS).
// ---------------------------------------------------------------------------
__global__ __launch_bounds__(256, 2) void linear_kernel(
    const float* __restrict__ x, const float* __restrict__ W,
    const float* __restrict__ bias, float* __restrict__ h) {
  __shared__ float Wt[128][68];   // Wt[k][c'] = W[cb+c'][k]; pad 68 keeps b128 align + staggers banks
  __shared__ float xs[64][132];   // xs[r][k]; pad 132 staggers banks, keeps float4 align

  const int t = threadIdx.x;
  const int row0 = (blockIdx.x >> 1) * 64;
  const int cb = (blockIdx.x & 1) * 64;
  const int nrows = (N_NODES - row0 < 64) ? (N_NODES - row0) : 64;

  // stage W half, transposed (one-time; minor bank conflicts acceptable)
  #pragma unroll
  for (int i = 0; i < 8; ++i) {
    int f4 = t + 256 * i;             // 0..2047 float4 slots
    int c = f4 >> 5;                  // 0..63
    int k = (f4 & 31) * 4;
    float4 v = *(const float4*)(W + (size_t)(cb + c) * 128 + k);
    Wt[k + 0][c] = v.x;
    Wt[k + 1][c] = v.y;
    Wt[k + 2][c] = v.z;
    Wt[k + 3][c] = v.w;
  }
  // stage x tile (coalesced float4, conflict-free writes)
  #pragma unroll
  for (int i = 0; i < 8; ++i) {
    int f4 = t + 256 * i;             // 0..2047
    int r = f4 >> 5;                  // 0..63
    int k = (f4 & 31) * 4;
    float4 v = make_float4(0.f, 0.f, 0.f, 0.f);
    if (r < nrows) v = *(const float4*)(x + (size_t)(row0 + r) * 128 + k);
    *(float4*)&xs[r][k] = v;
  }
  __syncthreads();

  const int tx = t & 15, ty4 = (t >> 4) * 4;
  float acc[4][4];
  #pragma unroll
  for (int i = 0; i < 4; ++i)
    #pragma unroll
    for (int j = 0; j < 4; ++j) acc[i][j] = 0.f;

  #pragma unroll 4
  for (int k = 0; k < 128; ++k) {
    float4 bv = *(const float4*)&Wt[k][tx * 4];
    float a0 = xs[ty4 + 0][k];
    float a1 = xs[ty4 + 1][k];
    float a2 = xs[ty4 + 2][k];
    float a3 = xs[ty4 + 3][k];
    acc[0][0] = fmaf(a0, bv.x, acc[0][0]);
    acc[0][1] = fmaf(a0, bv.y, acc[0][1]);
    acc[0][2] = fmaf(a0, bv.z, acc[0][2]);
    acc[0][3] = fmaf(a0, bv.w, acc[0][3]);
    acc[1][0] = fmaf(a1, bv.x, acc[1][0]);
    acc[1][1] = fmaf(a1, bv.y, acc[1][1]);
    acc[1][2] = fmaf(a1, bv.z, acc[1][2]);
    acc[1][3] = fmaf(a1, bv.w, acc[1][3]);
    acc[2][0] = fmaf(a2, bv.x, acc[2][0]);
    acc[2][1] = fmaf(a2, bv.y, acc[2][1]);
    acc[2][2] = fmaf(a2, bv.z, acc[2][2]);
    acc[2][3] = fmaf(a2, bv.w, acc[2][3]);
    acc[3][0] = fmaf(a3, bv.x, acc[3][0]);
    acc[3][1] = fmaf(a3, bv.y, acc[3][1]);
    acc[3][2] = fmaf(a3, bv.z, acc[3][2]);
    acc[3][3] = fmaf(a3, bv.w, acc[3][3]);
  }

  float4 bb = *(const float4*)(bias + cb + tx * 4);
  #pragma unroll
  for (int i = 0; i < 4; ++i) {
    int rl = ty4 + i;
    if (rl < nrows) {
      float4 o = make_float4(acc[i][0] + bb.x, acc[i][1] + bb.y,
                             acc[i][2] + bb.z, acc[i][3] + bb.w);
      *(float4*)(h + (size_t)(row0 + rl) * 128 + cb + tx * 4) = o;
    }
  }
}

// ---------------------------------------------------------------------------
// K2: histogram of dst into off[d+1]  (off pre-zeroed)
// ---------------------------------------------------------------------------
__global__ __launch_bounds__(256) void hist_kernel(const int* __restrict__ dst,
                                                   int* __restrict__ off) {
  int stride = gridDim.x * 256;
  for (int e = blockIdx.x * 256 + threadIdx.x; e < N_EDGES; e += stride)
    atomicAdd(&off[dst[e] + 1], 1);
}

// ---------------------------------------------------------------------------
// K3a/b/c: inclusive scan over off[0..N] (3-phase block scan)
// ---------------------------------------------------------------------------
__global__ __launch_bounds__(256) void scan1(int* __restrict__ off,
                                             int* __restrict__ bsum) {
  __shared__ int sh[256];
  int g = blockIdx.x * 256 + threadIdx.x;
  int v = (g < SCAN_LEN) ? off[g] : 0;
  sh[threadIdx.x] = v;
  __syncthreads();
  #pragma unroll
  for (int s = 1; s < 256; s <<= 1) {
    int u = (threadIdx.x >= s) ? sh[threadIdx.x - s] : 0;
    __syncthreads();
    sh[threadIdx.x] += u;
    __syncthreads();
  }
  if (g < SCAN_LEN) off[g] = sh[threadIdx.x];
  if (threadIdx.x == 255) bsum[blockIdx.x] = sh[255];
}

__global__ __launch_bounds__(512) void scan2(int* __restrict__ bsum) {
  __shared__ int sh[512];
  int t = threadIdx.x;
  int v = (t < SCAN_BLOCKS) ? bsum[t] : 0;
  sh[t] = v;
  __syncthreads();
  #pragma unroll
  for (int s = 1; s < 512; s <<= 1) {
    int u = (t >= s) ? sh[t - s] : 0;
    __syncthreads();
    sh[t] += u;
    __syncthreads();
  }
  if (t < SCAN_BLOCKS) bsum[t] = sh[t] - v;   // exclusive block offset
}

__global__ __launch_bounds__(256) void scan3(int* __restrict__ off,
                                             const int* __restrict__ bsum) {
  int g = blockIdx.x * 256 + threadIdx.x;
  if (g < SCAN_LEN) off[g] += bsum[blockIdx.x];
}

// ---------------------------------------------------------------------------
// K4: scatter edges into CSR slots (counting sort by dst)
// ---------------------------------------------------------------------------
__global__ __launch_bounds__(256) void scatter_kernel(
    const int* __restrict__ src, const int* __restrict__ dst,
    const float* __restrict__ w, int* __restrict__ cur,
    int* __restrict__ es, float* __restrict__ ew) {
  int stride = gridDim.x * 256;
  for (int e = blockIdx.x * 256 + threadIdx.x; e < N_EDGES; e += stride) {
    int d = dst[e];
    int p = atomicAdd(&cur[d], 1);
    es[p] = src[e];
    ew[p] = w[e];
  }
}

// ---------------------------------------------------------------------------
// K5: gather-aggregate. One wave per destination node; lane holds float2 of
// the 128-dim accumulator. Zero atomics; h reads are L3-resident gathers.
// ---------------------------------------------------------------------------
__global__ __launch_bounds__(256) void aggregate_kernel(
    const float* __restrict__ h, const int* __restrict__ off,
    const int* __restrict__ es, const float* __restrict__ ew,
    float* __restrict__ out) {
  int wid = threadIdx.x >> 6;
  int lane = threadIdx.x & 63;
  int d = blockIdx.x * 4 + wid;
  if (d >= N_NODES) return;
  int j0 = off[d], j1 = off[d + 1];
  const float2* h2 = (const float2*)h;
  float2 acc = make_float2(0.f, 0.f);
  int j = j0;
  for (; j + 2 <= j1; j += 2) {            // 2-edge unroll for ILP
    int s0 = es[j], s1 = es[j + 1];
    float w0 = ew[j], w1 = ew[j + 1];
    float2 v0 = h2[(size_t)s0 * 64 + lane];
    float2 v1 = h2[(size_t)s1 * 64 + lane];
    acc.x = fmaf(w0, v0.x, acc.x);
    acc.y = fmaf(w0, v0.y, acc.y);
    acc.x = fmaf(w1, v1.x, acc.x);
    acc.y = fmaf(w1, v1.y, acc.y);
  }
  if (j < j1) {
    int s0 = es[j];
    float w0 = ew[j];
    float2 v0 = h2[(size_t)s0 * 64 + lane];
    acc.x = fmaf(w0, v0.x, acc.x);
    acc.y = fmaf(w0, v0.y, acc.y);
  }
  ((float2*)out)[(size_t)d * 64 + lane] = acc;
}

// ---------------------------------------------------------------------------
// Fallback (only if ws too small for CSR): direct atomic scatter-add
// ---------------------------------------------------------------------------
__global__ __launch_bounds__(256) void edge_atomic_kernel(
    const float* __restrict__ h, const int* __restrict__ src,
    const int* __restrict__ dst, const float* __restrict__ w,
    float* __restrict__ out) {
  int wid = threadIdx.x >> 6;
  int lane = threadIdx.x & 63;
  long stride = (long)gridDim.x * 4;
  for (long e = (long)blockIdx.x * 4 + wid; e < N_EDGES; e += stride) {
    int s = src[e], d = dst[e];
    float wt = w[e];
    float2 v = ((const float2*)h)[(size_t)s * 64 + lane];
    atomicAdd(&out[(size_t)d * 128 + 2 * lane], wt * v.x);
    atomicAdd(&out[(size_t)d * 128 + 2 * lane + 1], wt * v.y);
  }
}

// ---------------------------------------------------------------------------
extern "C" void kernel_launch(void* const* d_in, const int* in_sizes, int n_in,
                              void* d_out, int out_size, void* d_ws, size_t ws_size,
                              hipStream_t stream) {
  const float* x = (const float*)d_in[0];
  const float* w = (const float*)d_in[1];
  const float* W = (const float*)d_in[2];
  const float* bias = (const float*)d_in[3];
  const int* src = (const int*)d_in[4];
  const int* dst = (const int*)d_in[5];
  float* out = (float*)d_out;

  // workspace layout
  char* p = (char*)d_ws;
  float* h = (float*)p;
  size_t o = (size_t)N_NODES * D * sizeof(float);                 // 51.2 MB
  int* off = (int*)(p + o);
  o = (o + (size_t)(N_NODES + 1) * 4 + 255) & ~(size_t)255;
  int* cur = (int*)(p + o);
  o = (o + (size_t)N_NODES * 4 + 255) & ~(size_t)255;
  int* es = (int*)(p + o);
  o += (size_t)N_EDGES * 4;
  float* ew = (float*)(p + o);
  o += (size_t)N_EDGES * 4;
  int* bsum = (int*)(p + o);
  size_t need = o + 4096;

  linear_kernel<<<3126, 256, 0, stream>>>(x, W, bias, h);

  if (ws_size >= need) {
    hipMemsetAsync(off, 0, (size_t)(N_NODES + 1) * sizeof(int), stream);
    hist_kernel<<<2048, 256, 0, stream>>>(dst, off);
    scan1<<<SCAN_BLOCKS, 256, 0, stream>>>(off, bsum);
    scan2<<<1, 512, 0, stream>>>(bsum);
    scan3<<<SCAN_BLOCKS, 256, 0, stream>>>(off, bsum);
    hipMemcpyAsync(cur, off, (size_t)N_NODES * sizeof(int),
                   hipMemcpyDeviceToDevice, stream);
    scatter_kernel<<<2048, 256, 0, stream>>>(src, dst, w, cur, es, ew);
    aggregate_kernel<<<25000, 256, 0, stream>>>(h, off, es, ew, out);
  } else {
    hipMemsetAsync(out, 0, (size_t)N_NODES * D * sizeof(float), stream);
    edge_atomic_kernel<<<12500, 256, 0, stream>>>(h, src, dst, w, out);
  }
}